// Round 2
// baseline (808.920 us; speedup 1.0000x reference)
//
#include <hip/hip_runtime.h>
#include <hip/hip_bf16.h>

// GeomEncoder: B=2048 batches, N=100 nodes, D=256, 4 dense-GAT layers.
// One workgroup per batch, everything resident in LDS, bf16 MFMA, fp32 I/O.

typedef __attribute__((ext_vector_type(8))) short bf16x8;  // 8 bf16 = 4 VGPRs
typedef __attribute__((ext_vector_type(4))) short bf16x4;  // 8 bytes
typedef __attribute__((ext_vector_type(4))) float f32x4;

__device__ __forceinline__ float bf2f(unsigned short u) {
    return __uint_as_float(((unsigned)u) << 16);
}
__device__ __forceinline__ short f2bfs(float f) {
    __hip_bfloat16 h = __float2bfloat16(f);   // RNE; compiler may pair into v_cvt_pk_bf16_f32
    return *reinterpret_cast<short*>(&h);
}

// ---- LDS layout (bytes) ----
// Hs : [112][256] bf16, row stride 512B, swizzled       ->  57344
// GsT: [256 feat][128 node] bf16, row stride 256B, swz  ->  65536
// P  : [112][128] bf16, row stride 256B, swz            ->  28672
// Ss/Sd: 112 f32 each; Xs: 600 f32
#define HS_OFF 0
#define GT_OFF 57344
#define P_OFF  122880
#define SS_OFF 151552
#define SD_OFF 152000
#define X_OFF  152448
#define SMEM_BYTES 154848

__device__ __forceinline__ int hs_addr(int row, int col) {
    return HS_OFF + row * 512 + ((col * 2) ^ ((row & 7) << 4));
}
__device__ __forceinline__ int gt_addr(int o, int n) {
    return GT_OFF + o * 256 + ((n * 2) ^ ((o & 7) << 4));
}
__device__ __forceinline__ int p_addr(int i, int j) {
    return P_OFF + i * 256 + ((j * 2) ^ ((i & 7) << 4));
}

struct LayerPtrs {
    const float* w[4];
    const float* bias[4];
};
struct PrepPtrs {
    const float* w[4];
    const float* as_[4];
    const float* ad_[4];
};

// ws[l] = W_l^T a_src_l, wd[l] = W_l^T a_dst_l  (batch-independent) -> d_ws as bf16
// layout: wsd[l*512 + 0..255] = ws, wsd[l*512 + 256..511] = wd
__global__ __launch_bounds__(256) void prep_kernel(PrepPtrs p, unsigned short* wsd) {
    const int l = blockIdx.x;
    const int d = threadIdx.x;
    __shared__ float As[256], Ad[256];
    As[d] = p.as_[l][d];
    Ad[d] = p.ad_[l][d];
    __syncthreads();
    const float* W = p.w[l];
    float s1 = 0.f, s2 = 0.f;
    for (int o = 0; o < 256; ++o) {
        float wv = W[o * 256 + d];         // coalesced across threads
        s1 = fmaf(wv, As[o], s1);
        s2 = fmaf(wv, Ad[o], s2);
    }
    wsd[l * 512 + d]       = (unsigned short)f2bfs(s1);
    wsd[l * 512 + 256 + d] = (unsigned short)f2bfs(s2);
}

__global__ __launch_bounds__(512) void geom_kernel(
    const float* __restrict__ x,        // [B,100,6] f32
    const float* __restrict__ remap_w,  // [256,6]
    const float* __restrict__ remap_b,  // [256]
    LayerPtrs lp,
    const unsigned short* __restrict__ wsd,  // prep output (bf16)
    float* __restrict__ out)            // [B,100,256] f32
{
    extern __shared__ char smem[];
    const int tid  = threadIdx.x;
    const int lane = tid & 63;
    const int wv   = tid >> 6;    // 0..7
    const int c    = lane & 15;   // MFMA row/col-within-tile index
    const int q    = lane >> 4;   // 0..3 k-group
    const int b    = blockIdx.x;

    // --- zero GsT + P pad regions (once; pads never rewritten) ---
    for (int off = tid * 16; off < (P_OFF + 28672) - GT_OFF; off += 512 * 16) {
        *(f32x4*)(smem + GT_OFF + off) = f32x4{0.f, 0.f, 0.f, 0.f};
    }
    // --- stage x for this batch ---
    float* Xs = (float*)(smem + X_OFF);
    const float* xb = x + (size_t)b * 600;
    for (int s = tid; s < 600; s += 512) Xs[s] = xb[s];
    __syncthreads();

    // --- remap: h = relu(x @ remap_w^T + remap_b), rows 100..111 zero ---
    {
        const int o = tid & 255, half = tid >> 8;
        float rw[6];
#pragma unroll
        for (int i = 0; i < 6; ++i) rw[i] = remap_w[o * 6 + i];
        const float rb = remap_b[o];
        for (int n = half * 56; n < half * 56 + 56; ++n) {
            float v = 0.f;
            if (n < 100) {
                v = rb;
#pragma unroll
                for (int i = 0; i < 6; ++i) v = fmaf(Xs[n * 6 + i], rw[i], v);
                v = fmaxf(v, 0.f);
            }
            *(unsigned short*)(smem + hs_addr(n, o)) = (unsigned short)f2bfs(v);
        }
    }

    float res[7][4][2];   // fp32 residual, static-indexed (loops unrolled)

    for (int l = 0; l < 4; ++l) {
        __syncthreads();   // Hs ready; GsT/P/Ss/Sd free
        const float* W = lp.w[l];
        const int nt0 = 2 * wv, nt1 = 2 * wv + 1;

        // ---------- phase A: g = h @ W^T  -> GsT (transposed, bf16) ----------
        {
            bf16x8 wf0[8], wf1[8];
            const float* p0 = W + (nt0 * 16 + c) * 256 + q * 8;
            const float* p1 = W + (nt1 * 16 + c) * 256 + q * 8;
#pragma unroll
            for (int kk = 0; kk < 8; ++kk) {
                f32x4 lo0 = *(const f32x4*)(p0 + kk * 32);
                f32x4 hi0 = *(const f32x4*)(p0 + kk * 32 + 4);
                f32x4 lo1 = *(const f32x4*)(p1 + kk * 32);
                f32x4 hi1 = *(const f32x4*)(p1 + kk * 32 + 4);
                bf16x8 w0, w1;
#pragma unroll
                for (int j = 0; j < 4; ++j) {
                    w0[j]     = f2bfs(lo0[j]);
                    w0[4 + j] = f2bfs(hi0[j]);
                    w1[j]     = f2bfs(lo1[j]);
                    w1[4 + j] = f2bfs(hi1[j]);
                }
                wf0[kk] = w0;
                wf1[kk] = w1;
            }
            for (int mt = 0; mt < 7; ++mt) {
                f32x4 a0e = {0,0,0,0}, a0o = {0,0,0,0}, a1e = {0,0,0,0}, a1o = {0,0,0,0};
#pragma unroll
                for (int kk = 0; kk < 8; kk += 2) {
                    bf16x8 afe = *(const bf16x8*)(smem + hs_addr(mt * 16 + c, kk * 32 + q * 8));
                    bf16x8 afo = *(const bf16x8*)(smem + hs_addr(mt * 16 + c, (kk + 1) * 32 + q * 8));
                    a0e = __builtin_amdgcn_mfma_f32_16x16x32_bf16(afe, wf0[kk],     a0e, 0, 0, 0);
                    a1e = __builtin_amdgcn_mfma_f32_16x16x32_bf16(afe, wf1[kk],     a1e, 0, 0, 0);
                    a0o = __builtin_amdgcn_mfma_f32_16x16x32_bf16(afo, wf0[kk + 1], a0o, 0, 0, 0);
                    a1o = __builtin_amdgcn_mfma_f32_16x16x32_bf16(afo, wf1[kk + 1], a1o, 0, 0, 0);
                }
                f32x4 a0 = a0e + a0o, a1 = a1e + a1o;
                bf16x4 g0, g1;
#pragma unroll
                for (int j = 0; j < 4; ++j) {
                    g0[j] = f2bfs(a0[j]);
                    g1[j] = f2bfs(a1[j]);
                }
                // D row = node mt*16+4q+j, D col = feature nt*16+c  ->  GsT[feat][node]
                *(bf16x4*)(smem + gt_addr(nt0 * 16 + c, mt * 16 + q * 4)) = g0;
                *(bf16x4*)(smem + gt_addr(nt1 * 16 + c, mt * 16 + q * 4)) = g1;
            }
            // ---------- scores: S = h @ [ws, wd] via MFMA (waves 0..6, rows wv*16..) ----------
            if (wv < 7) {
                const unsigned short* wsp = wsd + l * 512 + q * 8;
                const unsigned short* wdp = wsp + 256;
                f32x4 sa = {0,0,0,0};
#pragma unroll
                for (int kk = 0; kk < 8; ++kk) {
                    bf16x8 af = *(const bf16x8*)(smem + hs_addr(wv * 16 + c, kk * 32 + q * 8));
                    bf16x8 bs = *(const bf16x8*)(wsp + kk * 32);
                    bf16x8 bd = *(const bf16x8*)(wdp + kk * 32);
                    bf16x8 bz = {0,0,0,0,0,0,0,0};
                    bf16x8 bb = (c == 0) ? bs : ((c == 1) ? bd : bz);
                    sa = __builtin_amdgcn_mfma_f32_16x16x32_bf16(af, bb, sa, 0, 0, 0);
                }
                if (c < 2) {
                    float* dst = (float*)(smem + (c == 0 ? SS_OFF : SD_OFF));
#pragma unroll
                    for (int j = 0; j < 4; ++j) dst[wv * 16 + q * 4 + j] = sa[j];
                }
            }
        }
        __syncthreads();   // GsT, Ss/Sd ready

        // ---------- softmax over sources j per target i (4 lanes per row) ----------
        {
            const int i = tid >> 2, sq = tid & 3;
            if (i < 100) {
                const float sd = ((float*)(smem + SD_OFF))[i];
                const float* Ssf = (const float*)(smem + SS_OFF);
                float vals[4][8];
                float mx = -1e30f;
#pragma unroll
                for (int t = 0; t < 4; ++t) {
                    const int blk = t * 4 + sq;
#pragma unroll
                    for (int e = 0; e < 8; ++e) {
                        const int j = blk * 8 + e;
                        float v;
                        if (j < 100) {
                            float z = sd + Ssf[j];
                            v = (z > 0.f) ? z : 0.2f * z;   // leaky_relu 0.2
                        } else {
                            v = -1e30f;                      // K-pad -> exp 0
                        }
                        vals[t][e] = v;
                        mx = fmaxf(mx, v);
                    }
                }
                mx = fmaxf(mx, __shfl_xor(mx, 1, 4));
                mx = fmaxf(mx, __shfl_xor(mx, 2, 4));
                float sum = 0.f;
#pragma unroll
                for (int t = 0; t < 4; ++t)
#pragma unroll
                    for (int e = 0; e < 8; ++e) {
                        float ev = __expf(vals[t][e] - mx);
                        vals[t][e] = ev;
                        sum += ev;
                    }
                sum += __shfl_xor(sum, 1, 4);
                sum += __shfl_xor(sum, 2, 4);
                const float inv = 1.f / sum;
#pragma unroll
                for (int t = 0; t < 4; ++t) {
                    const int blk = t * 4 + sq;
                    bf16x8 pv;
#pragma unroll
                    for (int e = 0; e < 8; ++e) pv[e] = f2bfs(vals[t][e] * inv);
                    *(bf16x8*)(smem + p_addr(i, blk * 8)) = pv;
                }
            }
        }
        __syncthreads();   // P ready

        // ---------- PV: out = attn @ g (+bias, +residual, relu) ----------
        {
            const float* bias = lp.bias[l];
            const float b0 = bias[nt0 * 16 + c];
            const float b1 = bias[nt1 * 16 + c];
#pragma unroll
            for (int mt = 0; mt < 7; ++mt) {
                f32x4 a0e = {0,0,0,0}, a0o = {0,0,0,0}, a1e = {0,0,0,0}, a1o = {0,0,0,0};
#pragma unroll
                for (int kk = 0; kk < 4; kk += 2) {
                    bf16x8 afe = *(const bf16x8*)(smem + p_addr(mt * 16 + c, kk * 32 + q * 8));
                    bf16x8 afo = *(const bf16x8*)(smem + p_addr(mt * 16 + c, (kk + 1) * 32 + q * 8));
                    bf16x8 g0e = *(const bf16x8*)(smem + gt_addr(nt0 * 16 + c, kk * 32 + q * 8));
                    bf16x8 g1e = *(const bf16x8*)(smem + gt_addr(nt1 * 16 + c, kk * 32 + q * 8));
                    bf16x8 g0o = *(const bf16x8*)(smem + gt_addr(nt0 * 16 + c, (kk + 1) * 32 + q * 8));
                    bf16x8 g1o = *(const bf16x8*)(smem + gt_addr(nt1 * 16 + c, (kk + 1) * 32 + q * 8));
                    a0e = __builtin_amdgcn_mfma_f32_16x16x32_bf16(afe, g0e, a0e, 0, 0, 0);
                    a1e = __builtin_amdgcn_mfma_f32_16x16x32_bf16(afe, g1e, a1e, 0, 0, 0);
                    a0o = __builtin_amdgcn_mfma_f32_16x16x32_bf16(afo, g0o, a0o, 0, 0, 0);
                    a1o = __builtin_amdgcn_mfma_f32_16x16x32_bf16(afo, g1o, a1o, 0, 0, 0);
                }
                f32x4 a0 = a0e + a0o, a1 = a1e + a1o;
                const int row = mt * 16 + q * 4;
                if (l < 3) {
#pragma unroll
                    for (int j = 0; j < 4; ++j) {
                        {
                            const int ad = hs_addr(row + j, nt0 * 16 + c);
                            float r = (l == 0) ? bf2f(*(unsigned short*)(smem + ad))
                                               : res[mt][j][0];
                            float v = fmaxf(a0[j] + b0 + r, 0.f);
                            res[mt][j][0] = v;
                            *(unsigned short*)(smem + ad) = (unsigned short)f2bfs(v);
                        }
                        {
                            const int ad = hs_addr(row + j, nt1 * 16 + c);
                            float r = (l == 0) ? bf2f(*(unsigned short*)(smem + ad))
                                               : res[mt][j][1];
                            float v = fmaxf(a1[j] + b1 + r, 0.f);
                            res[mt][j][1] = v;
                            *(unsigned short*)(smem + ad) = (unsigned short)f2bfs(v);
                        }
                    }
                } else {
                    float* ob = out + (size_t)b * 25600;
#pragma unroll
                    for (int j = 0; j < 4; ++j) {
                        if (row + j < 100) {
                            ob[(row + j) * 256 + nt0 * 16 + c] = a0[j] + b0;
                            ob[(row + j) * 256 + nt1 * 16 + c] = a1[j] + b1;
                        }
                    }
                }
            }
        }
    }
}

extern "C" void kernel_launch(void* const* d_in, const int* in_sizes, int n_in,
                              void* d_out, int out_size, void* d_ws, size_t ws_size,
                              hipStream_t stream) {
    const float* x       = (const float*)d_in[0];
    const float* remap_w = (const float*)d_in[2];
    const float* remap_b = (const float*)d_in[3];
    PrepPtrs pp;
    LayerPtrs lp;
    for (int l = 0; l < 4; ++l) {
        lp.w[l]    = pp.w[l]   = (const float*)d_in[4 + 4 * l];
        pp.as_[l]  = (const float*)d_in[5 + 4 * l];
        pp.ad_[l]  = (const float*)d_in[6 + 4 * l];
        lp.bias[l] = (const float*)d_in[7 + 4 * l];
    }
    unsigned short* wsd = (unsigned short*)d_ws;

    prep_kernel<<<4, 256, 0, stream>>>(pp, wsd);

    (void)hipFuncSetAttribute(reinterpret_cast<const void*>(geom_kernel),
                              hipFuncAttributeMaxDynamicSharedMemorySize, SMEM_BYTES);
    geom_kernel<<<2048, 512, SMEM_BYTES, stream>>>(x, remap_w, remap_b, lp, wsd,
                                                   (float*)d_out);
}